// Round 2
// baseline (898.704 us; speedup 1.0000x reference)
//
#include <hip/hip_runtime.h>
#include <hip/hip_bf16.h>

typedef __bf16 bf16x8 __attribute__((ext_vector_type(8)));
typedef float  f32x4  __attribute__((ext_vector_type(4)));

#define LDS_BYTES 159744
// LDS region byte offsets (time-multiplexed):
//   [0,36864)        Xq  bf16[64][264]   -> Vt bf16[256][72]
//   [36864,70656)    Xkv bf16[64][264]
//   [70656,108544)   Ps  f32[256][37]    -> Qs bf16[64][264]  -> Fs f32[64][260] (with K region)
//   [108544,142336)  Ks  bf16[64][264]
//   [142336,159744)  Sc  f32[64][68]     -> At bf16[64][72] (overlay, barrier-protected)

__global__ void wconv_kernel(const float* __restrict__ Wq, const float* __restrict__ Wk,
                             const float* __restrict__ Wv, __bf16* __restrict__ o) {
    int i = blockIdx.x * 256 + threadIdx.x;   // grid = 256 blocks x 256 thr = 65536
    o[i]          = (__bf16)Wq[i];
    o[i + 65536]  = (__bf16)Wk[i];
    o[i + 131072] = (__bf16)Wv[i];
}

__launch_bounds__(512)
__global__ void fused_kernel(const float* __restrict__ Ci, const float* __restrict__ Pi1,
                             const __bf16* __restrict__ Wb, float* __restrict__ out)
{
    extern __shared__ char lds[];
    __bf16* Xq  = (__bf16*)(lds + 0);
    __bf16* Vt  = (__bf16*)(lds + 0);
    __bf16* Xkv = (__bf16*)(lds + 36864);
    float*  Ps  = (float*) (lds + 70656);
    __bf16* Qs  = (__bf16*)(lds + 70656);
    __bf16* Ks  = (__bf16*)(lds + 108544);
    float*  Sc  = (float*) (lds + 142336);
    __bf16* At  = (__bf16*)(lds + 142336);
    float*  Fs  = (float*) (lds + 70656);

    const int t    = threadIdx.x;
    const int lane = t & 63;
    const int wv   = t >> 6;     // wave 0..7
    const int l15  = lane & 15;
    const int lk   = lane >> 4;  // 0..3

    int bid = blockIdx.x;
    bid = (bid & 7) * 512 + (bid >> 3);   // XCD-contiguous swizzle (bijective: 4096 % 8 == 0)
    const int b   = bid >> 8;
    const int win = bid & 255;
    const int wh  = win >> 4, ww = win & 15;
    const int h0  = wh * 8, w0 = ww * 8;

    const __bf16* Wqb = Wb;
    const __bf16* Wkb = Wb + 65536;
    const __bf16* Wvb = Wb + 131072;

    // ---- Phase L: Ci window -> Xq (bf16); Pi1 6x6 halo region -> Ps (f32) ----
    {
        const int c = t >> 1, j = t & 1;
        const float* src = Ci + ((size_t)(b * 256 + c) * 128 + h0) * 128 + w0;
        #pragma unroll
        for (int r = 0; r < 4; ++r) {
            const int ph = 4 * j + r;
            const float4 v0 = *(const float4*)(src + ph * 128);
            const float4 v1 = *(const float4*)(src + ph * 128 + 4);
            __bf16* dst = Xq + (ph * 8) * 264 + c;
            dst[0*264] = (__bf16)v0.x; dst[1*264] = (__bf16)v0.y;
            dst[2*264] = (__bf16)v0.z; dst[3*264] = (__bf16)v0.w;
            dst[4*264] = (__bf16)v1.x; dst[5*264] = (__bf16)v1.y;
            dst[6*264] = (__bf16)v1.z; dst[7*264] = (__bf16)v1.w;
        }
        const int iy0 = wh * 4 - 1, ix0 = ww * 4 - 1;
        const float* psrc = Pi1 + (size_t)(b * 256 + c) * 4096;
        #pragma unroll
        for (int rr = 0; rr < 3; ++rr) {
            const int iy = 3 * j + rr;
            const int gy = min(max(iy0 + iy, 0), 63);
            #pragma unroll
            for (int ix = 0; ix < 6; ++ix) {
                const int gx = min(max(ix0 + ix, 0), 63);
                Ps[c * 37 + iy * 6 + ix] = psrc[gy * 64 + gx];
            }
        }
    }
    __syncthreads();

    // ---- Phase U: bilinear 2x upsample -> Xkv (bf16) ----
    // jax.image.resize half-pixel: out coord o/2-0.25.
    //   even ph: local idx ph/2   taps (0.25, 0.75)
    //   odd  ph: local idx ph/2+1 taps (0.75, 0.25)   (edges via clamped staging)
    {
        const int c = t & 255, half = t >> 8;
        const float* P = Ps + c * 37;
        #pragma unroll
        for (int pp = 0; pp < 32; ++pp) {
            const int p = half * 32 + pp;
            const int ph = p >> 3, pw = p & 7;
            const int ly = (ph & 1) ? (ph >> 1) + 1 : (ph >> 1);
            const float wy = (ph & 1) ? 0.75f : 0.25f;
            const int lx = (pw & 1) ? (pw >> 1) + 1 : (pw >> 1);
            const float wx = (pw & 1) ? 0.75f : 0.25f;
            const float r0 = wx * P[ly * 6 + lx]       + (1.0f - wx) * P[ly * 6 + lx + 1];
            const float r1 = wx * P[(ly + 1) * 6 + lx] + (1.0f - wx) * P[(ly + 1) * 6 + lx + 1];
            Xkv[p * 264 + c] = (__bf16)(wy * r0 + (1.0f - wy) * r1);
        }
    }
    __syncthreads();

    // ---- Phase QP: Q = Xq * Wq^T (per-wave 32 out-channels) ----
    {
        const int ob = wv * 32;
        f32x4 acc[4][2];
        #pragma unroll
        for (int mt = 0; mt < 4; ++mt) { acc[mt][0] = f32x4{0.f,0.f,0.f,0.f}; acc[mt][1] = f32x4{0.f,0.f,0.f,0.f}; }
        for (int k0 = 0; k0 < 256; k0 += 32) {
            bf16x8 a[4], bw[2];
            #pragma unroll
            for (int mt = 0; mt < 4; ++mt)
                a[mt] = *(const bf16x8*)(Xq + (mt * 16 + l15) * 264 + k0 + lk * 8);
            #pragma unroll
            for (int nt = 0; nt < 2; ++nt)
                bw[nt] = *(const bf16x8*)(Wqb + (ob + nt * 16 + l15) * 256 + k0 + lk * 8);
            #pragma unroll
            for (int mt = 0; mt < 4; ++mt)
                #pragma unroll
                for (int nt = 0; nt < 2; ++nt)
                    acc[mt][nt] = __builtin_amdgcn_mfma_f32_16x16x32_bf16(a[mt], bw[nt], acc[mt][nt], 0, 0, 0);
        }
        #pragma unroll
        for (int mt = 0; mt < 4; ++mt)
            #pragma unroll
            for (int nt = 0; nt < 2; ++nt)
                #pragma unroll
                for (int r = 0; r < 4; ++r)
                    Qs[(mt * 16 + lk * 4 + r) * 264 + ob + nt * 16 + l15] = (__bf16)acc[mt][nt][r];
    }
    __syncthreads();

    // ---- Phase KVP: K = Xkv*Wk^T -> Ks ; V = Xkv*Wv^T -> Vt (transposed) ----
    {
        const int ob = wv * 32;
        f32x4 ak[4][2], av[4][2];
        #pragma unroll
        for (int mt = 0; mt < 4; ++mt) {
            ak[mt][0] = f32x4{0.f,0.f,0.f,0.f}; ak[mt][1] = f32x4{0.f,0.f,0.f,0.f};
            av[mt][0] = f32x4{0.f,0.f,0.f,0.f}; av[mt][1] = f32x4{0.f,0.f,0.f,0.f};
        }
        for (int k0 = 0; k0 < 256; k0 += 32) {
            bf16x8 a[4], bk[2], bv[2];
            #pragma unroll
            for (int mt = 0; mt < 4; ++mt)
                a[mt] = *(const bf16x8*)(Xkv + (mt * 16 + l15) * 264 + k0 + lk * 8);
            #pragma unroll
            for (int nt = 0; nt < 2; ++nt) {
                bk[nt] = *(const bf16x8*)(Wkb + (ob + nt * 16 + l15) * 256 + k0 + lk * 8);
                bv[nt] = *(const bf16x8*)(Wvb + (ob + nt * 16 + l15) * 256 + k0 + lk * 8);
            }
            #pragma unroll
            for (int mt = 0; mt < 4; ++mt)
                #pragma unroll
                for (int nt = 0; nt < 2; ++nt) {
                    ak[mt][nt] = __builtin_amdgcn_mfma_f32_16x16x32_bf16(a[mt], bk[nt], ak[mt][nt], 0, 0, 0);
                    av[mt][nt] = __builtin_amdgcn_mfma_f32_16x16x32_bf16(a[mt], bv[nt], av[mt][nt], 0, 0, 0);
                }
        }
        #pragma unroll
        for (int mt = 0; mt < 4; ++mt)
            #pragma unroll
            for (int nt = 0; nt < 2; ++nt) {
                #pragma unroll
                for (int r = 0; r < 4; ++r)
                    Ks[(mt * 16 + lk * 4 + r) * 264 + ob + nt * 16 + l15] = (__bf16)ak[mt][nt][r];
                const int cc = ob + nt * 16 + l15;
                __bf16* d = Vt + cc * 72 + mt * 16 + lk * 4;   // V^T[c][pixel], 4 consecutive pixels
                d[0] = (__bf16)av[mt][nt][0]; d[1] = (__bf16)av[mt][nt][1];
                d[2] = (__bf16)av[mt][nt][2]; d[3] = (__bf16)av[mt][nt][3];
            }
    }
    __syncthreads();

    // ---- Phase S: scores = Q*K^T -> Sc (f32) ----
    {
        const int mt = wv >> 1, nh = wv & 1;
        f32x4 a0 = f32x4{0.f,0.f,0.f,0.f}, a1 = f32x4{0.f,0.f,0.f,0.f};
        for (int k0 = 0; k0 < 256; k0 += 32) {
            bf16x8 aq = *(const bf16x8*)(Qs + (mt * 16 + l15) * 264 + k0 + lk * 8);
            bf16x8 b0 = *(const bf16x8*)(Ks + (nh * 32 + l15) * 264 + k0 + lk * 8);
            bf16x8 b1 = *(const bf16x8*)(Ks + (nh * 32 + 16 + l15) * 264 + k0 + lk * 8);
            a0 = __builtin_amdgcn_mfma_f32_16x16x32_bf16(aq, b0, a0, 0, 0, 0);
            a1 = __builtin_amdgcn_mfma_f32_16x16x32_bf16(aq, b1, a1, 0, 0, 0);
        }
        #pragma unroll
        for (int r = 0; r < 4; ++r) {
            Sc[(mt * 16 + lk * 4 + r) * 68 + nh * 32 + l15]      = a0[r];
            Sc[(mt * 16 + lk * 4 + r) * 68 + nh * 32 + 16 + l15] = a1[r];
        }
    }
    __syncthreads();

    // ---- Softmax (scale 1/16), write attn bf16 into overlay of Sc ----
    {
        const int row = t >> 3, kj = t & 7;
        const float* sr = Sc + row * 68 + kj * 8;
        float s[8];
        #pragma unroll
        for (int i = 0; i < 8; ++i) s[i] = sr[i];
        float m = s[0];
        #pragma unroll
        for (int i = 1; i < 8; ++i) m = fmaxf(m, s[i]);
        m = fmaxf(m, __shfl_xor(m, 1));
        m = fmaxf(m, __shfl_xor(m, 2));
        m = fmaxf(m, __shfl_xor(m, 4));
        float e[8], sum = 0.f;
        #pragma unroll
        for (int i = 0; i < 8; ++i) { e[i] = __expf((s[i] - m) * 0.0625f); sum += e[i]; }
        sum += __shfl_xor(sum, 1);
        sum += __shfl_xor(sum, 2);
        sum += __shfl_xor(sum, 4);
        const float rs = 1.0f / sum;
        __syncthreads();                       // everyone holds regs; safe to overlay
        __bf16* ar = At + row * 72 + kj * 8;
        #pragma unroll
        for (int i = 0; i < 8; ++i) ar[i] = (__bf16)(e[i] * rs);
    }
    __syncthreads();

    // ---- Phase PV: F = attn * V -> Fs (f32, overlays Qs+Ks) ----
    {
        const int mt = wv >> 1, ch = wv & 1;
        f32x4 acc[8];
        #pragma unroll
        for (int nt = 0; nt < 8; ++nt) acc[nt] = f32x4{0.f,0.f,0.f,0.f};
        #pragma unroll
        for (int kk = 0; kk < 64; kk += 32) {
            bf16x8 a = *(const bf16x8*)(At + (mt * 16 + l15) * 72 + kk + lk * 8);
            #pragma unroll
            for (int nt = 0; nt < 8; ++nt) {
                bf16x8 bb = *(const bf16x8*)(Vt + (ch * 128 + nt * 16 + l15) * 72 + kk + lk * 8);
                acc[nt] = __builtin_amdgcn_mfma_f32_16x16x32_bf16(a, bb, acc[nt], 0, 0, 0);
            }
        }
        #pragma unroll
        for (int nt = 0; nt < 8; ++nt)
            #pragma unroll
            for (int r = 0; r < 4; ++r)
                Fs[(mt * 16 + lk * 4 + r) * 260 + ch * 128 + nt * 16 + l15] = acc[nt][r];
    }
    __syncthreads();

    // ---- Epilogue: out = Ci + F (coalesced float4) ----
    {
        const int c = t >> 1, j = t & 1;
        const size_t base = ((size_t)(b * 256 + c) * 128 + h0) * 128 + w0;
        const float* csrc = Ci + base;
        float* dst = out + base;
        #pragma unroll
        for (int r = 0; r < 4; ++r) {
            const int ph = 4 * j + r;
            const float4 v0 = *(const float4*)(csrc + ph * 128);
            const float4 v1 = *(const float4*)(csrc + ph * 128 + 4);
            const float* f = Fs + (ph * 8) * 260 + c;
            float4 o0, o1;
            o0.x = v0.x + f[0 * 260]; o0.y = v0.y + f[1 * 260];
            o0.z = v0.z + f[2 * 260]; o0.w = v0.w + f[3 * 260];
            o1.x = v1.x + f[4 * 260]; o1.y = v1.y + f[5 * 260];
            o1.z = v1.z + f[6 * 260]; o1.w = v1.w + f[7 * 260];
            *(float4*)(dst + ph * 128)     = o0;
            *(float4*)(dst + ph * 128 + 4) = o1;
        }
    }
}

extern "C" void kernel_launch(void* const* d_in, const int* in_sizes, int n_in,
                              void* d_out, int out_size, void* d_ws, size_t ws_size,
                              hipStream_t stream) {
    const float* Ci  = (const float*)d_in[0];
    const float* Pi1 = (const float*)d_in[1];
    const float* Wq  = (const float*)d_in[2];
    const float* Wk  = (const float*)d_in[3];
    const float* Wv  = (const float*)d_in[4];
    float* out = (float*)d_out;
    __bf16* Wb = (__bf16*)d_ws;    // 3 * 65536 bf16 = 384 KB

    wconv_kernel<<<256, 256, 0, stream>>>(Wq, Wk, Wv, Wb);

    hipFuncSetAttribute(reinterpret_cast<const void*>(&fused_kernel),
                        hipFuncAttributeMaxDynamicSharedMemorySize, LDS_BYTES);
    fused_kernel<<<4096, 512, LDS_BYTES, stream>>>(Ci, Pi1, Wb, out);
}